// Round 26
// baseline (171.810 us; speedup 1.0000x reference)
//
#include <hip/hip_runtime.h>
#include <math.h>

#define BN   2
#define CIN  96
#define HH   40
#define WW   40
#define LL   1600
#define DIN  192
#define NS   16
#define RR   6
#define KK   4
#define CH   25   // chunk length per lane (LL/64)

typedef _Float16 h16;

__device__ __forceinline__ float sigmoidf_(float x){ return 1.0f/(1.0f+expf(-x)); }
__device__ __forceinline__ float softplus_fast(float x){
  return x > 20.0f ? x : __logf(1.0f + __expf(x));
}

// p[i] = R^(i+1) for i=0..15, log-depth tree (depth ~4, 15 muls)
__device__ __forceinline__ void pow_tree(float R, float* p){
  float R2 = R * R;
  float R4 = R2 * R2;
  float R8 = R4 * R4;
  p[0]  = R;        p[1]  = R2;       p[2]  = R2 * R;   p[3]  = R4;
  p[4]  = R4 * R;   p[5]  = R4 * R2;  p[6]  = R4 * p[2];p[7]  = R8;
  p[8]  = R8 * R;   p[9]  = R8 * R2;  p[10] = R8 * p[2];p[11] = R8 * R4;
  p[12] = R8 * p[4];p[13] = R8 * p[5];p[14] = R8 * p[6];p[15] = R8 * R8;
}

__device__ __forceinline__ void unpack8(float4 v, float* dst){
  const h16* hp = reinterpret_cast<const h16*>(&v);
  #pragma unroll
  for (int i = 0; i < 8; ++i) dst[i] = (float)hp[i];
}

// ------ K1: FUSED in_proj + depthwise 3x3 + bias + SiLU + chunk emit + SE mean
// grid: (DIN, 2*B) = 768 blocks, 256 thr. The in_proj row for (d, mb) is
// computed in registers: weight row block-uniform (scalar loads); per-
// channel pixel loads coalesced; L2-resident x reuse across the 192 d-blocks.
// xproj global round-trip and its kernel launch are ELIMINATED.
__global__ void k_conv(const float* __restrict__ x_rgb, const float* __restrict__ x_e,
                       const float* __restrict__ in_w, const float* __restrict__ in_mx_w,
                       const float* __restrict__ conv_w, const float* __restrict__ conv_b,
                       h16* __restrict__ u_chA, h16* __restrict__ u_chT,
                       float* __restrict__ sq){
  __shared__ float pl[LL];
  __shared__ float sact[LL + HH];    // padded: index l + l/40
  __shared__ float red[4];
  int d  = blockIdx.x;
  int mb = blockIdx.y;
  int m = mb / BN, b = mb % BN;
  const float* xsrc = (m == 0 ? x_rgb : x_e) + (size_t)b * CIN * LL;
  const float* wrow = (m == 0 ? in_w : in_mx_w) + d * CIN;
  int tid = threadIdx.x;
  // in_proj row d: acc[j] covers pixel tid + j*256 (j=6 partial, tid<64)
  float acc7[7];
  #pragma unroll
  for (int j = 0; j < 7; ++j) acc7[j] = 0.f;
  for (int c = 0; c < CIN; ++c){
    float wc = wrow[c];                       // block-uniform scalar
    const float* xr = xsrc + (size_t)c * LL;
    #pragma unroll
    for (int j = 0; j < 6; ++j)
      acc7[j] += wc * xr[tid + j * 256];      // coalesced
    if (tid < 64) acc7[6] += wc * xr[tid + 1536];
  }
  #pragma unroll
  for (int j = 0; j < 6; ++j) pl[tid + j * 256] = acc7[j];
  if (tid < 64) pl[tid + 1536] = acc7[6];
  __syncthreads();
  float cw[9];
  #pragma unroll
  for (int j = 0; j < 9; ++j) cw[j] = conv_w[d * 9 + j];
  float bias = conv_b[d];
  float lsum = 0.f;
  for (int p = tid; p < LL; p += 256){
    int py = p / WW, px = p % WW;
    float acc = bias;
    #pragma unroll
    for (int dy = -1; dy <= 1; ++dy){
      int yy = py + dy;
      if (yy < 0 || yy >= HH) continue;
      #pragma unroll
      for (int dx = -1; dx <= 1; ++dx){
        int xx = px + dx;
        if (xx < 0 || xx >= WW) continue;
        acc += cw[(dy + 1) * 3 + (dx + 1)] * pl[yy * WW + xx];
      }
    }
    float s = acc * sigmoidf_(acc);
    sact[p + p / WW] = s;
    lsum += s;
  }
  #pragma unroll
  for (int off = 32; off; off >>= 1) lsum += __shfl_down(lsum, off);
  if ((tid & 63) == 0) red[tid >> 6] = lsum;
  __syncthreads();
  if (tid == 0)
    sq[mb * DIN + d] = (red[0] + red[1] + red[2] + red[3]) * (1.0f / LL);
  size_t po = ((size_t)mb * DIN + d) * LL;
  h16* uA = u_chA + po;
  h16* uT = u_chT + po;
  for (int q = tid; q < LL; q += 256){
    int l = (q & 63) * CH + (q >> 6);
    uA[q] = (h16)sact[l + l / WW];
    int pt = (l % WW) * WW + l / WW;
    uT[q] = (h16)sact[pt + pt / WW];
  }
}

// ------ K2: x_proj + FUSED dt-projection/softplus — Q-TILED --------------
// grid: (25, K*2, 2*B), block 256. Block bx covers chunk indices
// q in [64*bx, 64*bx+64): x reads straight from u_chA/u_chT (coalesced,
// reversed dirs via chunk-map identity); B/C/dsp writes q-contiguous.
__global__ void k_xproj(const h16* __restrict__ u_chA, const h16* __restrict__ u_chT,
                        const float* __restrict__ xp1, const float* __restrict__ xp2,
                        const float* __restrict__ dtw1, const float* __restrict__ dtb1,
                        const float* __restrict__ dtw2, const float* __restrict__ dtb2,
                        h16* __restrict__ B_ch, h16* __restrict__ C_ch,
                        h16* __restrict__ dsp_all){
  __shared__ h16 xs[DIN][64];           // 24 KB staged tile
  __shared__ float td[RR][64];
  int bx = blockIdx.x;                  // s-row; q0 = bx*64
  int k  = blockIdx.y >> 1;
  int hf = blockIdx.y & 1;              // channel half
  int mb = blockIdx.z; int m = mb / BN;
  const float* xw = (m == 0 ? xp1 : xp2) + k * 38 * DIN;
  const h16* xa = ((k & 1) ? u_chT : u_chA) + (size_t)mb * DIN * LL;
  bool rev = (k >= 2);
  int qrbase = rev ? ((24 - bx) * 64) : (bx * 64);
  for (int idx = threadIdx.x; idx < DIN * 64; idx += 256){
    int dd = idx >> 6, sl = idx & 63;
    int qr = rev ? (qrbase + 63 - sl) : (qrbase + sl);
    xs[dd][sl] = xa[(size_t)dd * LL + qr];
  }
  __syncthreads();
  int ll = threadIdx.x & 63;
  int g  = __builtin_amdgcn_readfirstlane(threadIdx.x >> 6);  // wave-uniform
  int c0 = (hf * 4 + g) * 5;            // 8 slots x 5 channels (40 >= 38)
  float acc[5];
  #pragma unroll
  for (int i = 0; i < 5; ++i) acc[i] = 0.f;
  for (int dd = 0; dd < DIN; ++dd){
    float xv = (float)xs[dd][ll];
    #pragma unroll
    for (int i = 0; i < 5; ++i){
      int cc = c0 + i; if (cc > 37) cc = 37;      // clamp (uniform, in-bounds)
      acc[i] += xw[cc * DIN + dd] * xv;           // scalar s_load
    }
  }
  int mbk = mb * KK + k;
  int q = bx * 64 + ll;                 // chunk index (contiguous per wave)
  int nc = 38 - c0; if (nc > 5) nc = 5;
  for (int i = 0; i < nc; ++i){
    int c = c0 + i;
    float v = acc[i];
    if (c < RR){
      td[c][ll] = v;                    // dt rows stay in LDS (half 0 only)
    } else if (c < RR + NS){
      int n = c - RR;
      B_ch[(((size_t)mbk * 2 + (n >> 3)) * LL + q) * 8 + (n & 7)] = (h16)v;
    } else {
      int n = c - RR - NS;
      C_ch[(((size_t)mbk * 2 + (n >> 3)) * LL + q) * 8 + (n & 7)] = (h16)v;
    }
  }
  if (hf == 0){
    __syncthreads();
    const float* dtw = (m == 0 ? dtw1 : dtw2);
    const float* dtb = (m == 0 ? dtb1 : dtb2);
    h16* dsp = dsp_all + (size_t)mbk * DIN * LL;
    for (int idx = threadIdx.x; idx < DIN * 64; idx += 256){
      int dd = __builtin_amdgcn_readfirstlane(idx >> 6);   // wave-uniform
      int px = idx & 63;
      int kd = k * DIN + dd;
      const float* w = dtw + kd * RR;
      float a = dtb[kd];
      #pragma unroll
      for (int r = 0; r < RR; ++r) a += w[r] * td[r][px];
      dsp[(size_t)dd * LL + bx * 64 + px] = (h16)softplus_fast(a);  // q-order
    }
  }
}

// ---------------- K3: chunked parallel selective scan -------------------
// ONE WAVE PER CHAIN, 16 states in registers, wave-private LDS (no barrier,
// no atomic). q-ordered dsp joins the DEPTH-2 pipeline directly.
// grid: 768 blocks of 256. y_px HALF [chain][pixel]
__global__ void __launch_bounds__(256, 3) k_scan(
    const h16* __restrict__ u_chA, const h16* __restrict__ u_chT,
    const h16* __restrict__ dsp_all, const h16* __restrict__ B_ch,
    const h16* __restrict__ C_ch,
    const float* __restrict__ Alog1, const float* __restrict__ Alog2,
    const float* __restrict__ D1, const float* __restrict__ D2,
    h16* __restrict__ y_px){
  __shared__ h16 ysth[4][LL];               // [wave][l]  (wave-private)
  int wv   = threadIdx.x >> 6;
  int lane = threadIdx.x & 63;
  int chain = blockIdx.x * 4 + wv;          // = (mb*KK + k)*DIN + d
  int d   = chain % DIN;
  int mbk = chain / DIN;
  int k   = mbk % KK;
  int mb  = mbk / KK;
  int m = mb / BN, b = mb % BN;
  int kd = k * DIN + d;
  bool rev = (k >= 2);

  const float* Alog = (m == 0 ? Alog1 : Alog2) + kd * NS;
  float An[NS];
  bool fastA = true;
  #pragma unroll
  for (int n = 0; n < NS; ++n){
    An[n] = -__expf(Alog[n]);
    fastA = fastA && (fabsf(An[n] + (float)(n + 1)) <= 1e-4f * (float)(n + 1));
  }
  float Dv = (m == 0 ? D2 : D1)[kd];

  const h16* dsp_row = dsp_all + (size_t)chain * LL;   // q-ordered
  const float4* B0 = reinterpret_cast<const float4*>(B_ch) + (size_t)mbk * 2 * LL;
  int mbk_o = ((1 - m) * BN + b) * KK + k;              // other modality's C
  const float4* C0 = reinterpret_cast<const float4*>(C_ch) + (size_t)mbk_o * 2 * LL;
  const h16* urow = ((k & 1) ? u_chT : u_chA) + ((size_t)mb * DIN + d) * LL;

  float h[NS];
  #pragma unroll
  for (int n = 0; n < NS; ++n) h[n] = 0.f;
  float Sdt = 0.f;

  if (fastA){
    // ---- phase 1, depth-2 pipeline (named A/B sets, static indices) ----
    float4 bA0, bA1, cA0, cA1, bB0, bB1, cB0, cB1;
    float uA_, uB_, dtA_, dtB_;
    {
      int qa = lane;
      dtA_ = (float)dsp_row[qa];
      uA_  = (float)urow[rev ? (LL - 1 - qa) : qa];
      bA0 = B0[qa]; bA1 = B0[LL + qa];
      cA0 = C0[qa]; cA1 = C0[LL + qa];
      int qb = 64 + lane;
      dtB_ = (float)dsp_row[qb];
      uB_  = (float)urow[rev ? (LL - 1 - qb) : qb];
      bB0 = B0[qb]; bB1 = B0[LL + qb];
      cB0 = C0[qb]; cB1 = C0[LL + qb];
    }
    for (int s = 0; s < CH - 1; s += 2){
      {
        float dt = dtA_, u = uA_;
        float4 b0 = bA0, b1 = bA1, c0 = cA0, c1 = cA1;
        if (s + 2 < CH){
          int q2 = (s + 2) * 64 + lane;
          dtA_ = (float)dsp_row[q2];
          uA_  = (float)urow[rev ? (LL - 1 - q2) : q2];
          bA0 = B0[q2]; bA1 = B0[LL + q2];
          cA0 = C0[q2]; cA1 = C0[LL + q2];
        }
        Sdt += dt;
        float du = dt * u;
        float Bv[NS], Cv[NS];
        unpack8(b0, Bv); unpack8(b1, Bv + 8);
        unpack8(c0, Cv); unpack8(c1, Cv + 8);
        float p[NS];
        pow_tree(__expf(-dt), p);
        float y0 = Dv * u, y1 = 0.f, y2 = 0.f, y3 = 0.f;
        #pragma unroll
        for (int n = 0; n < NS; ++n){
          h[n] = p[n] * h[n] + du * Bv[n];
          float t = h[n] * Cv[n];
          if      ((n & 3) == 0) y0 += t;
          else if ((n & 3) == 1) y1 += t;
          else if ((n & 3) == 2) y2 += t;
          else                   y3 += t;
        }
        ysth[wv][lane * CH + s] = (h16)((y0 + y1) + (y2 + y3));
      }
      {
        float dt = dtB_, u = uB_;
        float4 b0 = bB0, b1 = bB1, c0 = cB0, c1 = cB1;
        if (s + 3 < CH){
          int q3 = (s + 3) * 64 + lane;
          dtB_ = (float)dsp_row[q3];
          uB_  = (float)urow[rev ? (LL - 1 - q3) : q3];
          bB0 = B0[q3]; bB1 = B0[LL + q3];
          cB0 = C0[q3]; cB1 = C0[LL + q3];
        }
        Sdt += dt;
        float du = dt * u;
        float Bv[NS], Cv[NS];
        unpack8(b0, Bv); unpack8(b1, Bv + 8);
        unpack8(c0, Cv); unpack8(c1, Cv + 8);
        float p[NS];
        pow_tree(__expf(-dt), p);
        float y0 = Dv * u, y1 = 0.f, y2 = 0.f, y3 = 0.f;
        #pragma unroll
        for (int n = 0; n < NS; ++n){
          h[n] = p[n] * h[n] + du * Bv[n];
          float t = h[n] * Cv[n];
          if      ((n & 3) == 0) y0 += t;
          else if ((n & 3) == 1) y1 += t;
          else if ((n & 3) == 2) y2 += t;
          else                   y3 += t;
        }
        ysth[wv][lane * CH + s + 1] = (h16)((y0 + y1) + (y2 + y3));
      }
    }
    {
      const int s = CH - 1;
      float dt = dtA_, u = uA_;
      Sdt += dt;
      float du = dt * u;
      float Bv[NS], Cv[NS];
      unpack8(bA0, Bv); unpack8(bA1, Bv + 8);
      unpack8(cA0, Cv); unpack8(cA1, Cv + 8);
      float p[NS];
      pow_tree(__expf(-dt), p);
      float y0 = Dv * u, y1 = 0.f, y2 = 0.f, y3 = 0.f;
      #pragma unroll
      for (int n = 0; n < NS; ++n){
        h[n] = p[n] * h[n] + du * Bv[n];
        float t = h[n] * Cv[n];
        if      ((n & 3) == 0) y0 += t;
        else if ((n & 3) == 1) y1 += t;
        else if ((n & 3) == 2) y2 += t;
        else                   y3 += t;
      }
      ysth[wv][lane * CH + s] = (h16)((y0 + y1) + (y2 + y3));
    }
  } else {
    #pragma unroll 5
    for (int s = 0; s < CH; ++s){
      int q = s * 64 + lane;
      float dt = (float)dsp_row[q];
      Sdt += dt;
      float u  = (float)urow[rev ? (LL - 1 - q) : q];
      float du = dt * u;
      float Bv[NS], Cv[NS];
      unpack8(B0[q], Bv); unpack8(B0[LL + q], Bv + 8);
      unpack8(C0[q], Cv); unpack8(C0[LL + q], Cv + 8);
      float y0 = Dv * u, y1 = 0.f, y2 = 0.f, y3 = 0.f;
      #pragma unroll
      for (int n = 0; n < NS; ++n){
        float dA = __expf(dt * An[n]);
        h[n] = dA * h[n] + du * Bv[n];
        float t = h[n] * Cv[n];
        if      ((n & 3) == 0) y0 += t;
        else if ((n & 3) == 1) y1 += t;
        else if ((n & 3) == 2) y2 += t;
        else                   y3 += t;
      }
      ysth[wv][lane * CH + s] = (h16)((y0 + y1) + (y2 + y3));
    }
  }
  float aP[NS];
  if (fastA){
    pow_tree(__expf(-Sdt), aP);
  } else {
    #pragma unroll
    for (int n = 0; n < NS; ++n) aP[n] = __expf(Sdt * An[n]);
  }

  // Kogge-Stone inclusive scan of (aP,h) across 64 lanes (chunk order)
  #pragma unroll
  for (int off = 1; off < 64; off <<= 1){
    #pragma unroll
    for (int n = 0; n < NS; ++n){
      float ap = __shfl_up(aP[n], off);
      float bp = __shfl_up(h[n],  off);
      if (lane >= off){
        h[n]  = aP[n] * bp + h[n];
        aP[n] = aP[n] * ap;
      }
    }
  }
  // carry-in for this chunk = inclusive result of previous lane
  #pragma unroll
  for (int n = 0; n < NS; ++n){
    float v = __shfl_up(h[n], 1);
    h[n] = (lane == 0) ? 0.f : v;      // h[] now holds the carry
  }

  // phase 2: correction pass — ysth[l] += sum_n carry[n]*E_s^(n+1)*C[n]
  if (fastA){
    float4 cA0, cA1, cB0, cB1;
    float dtA_, dtB_;
    {
      int qa = lane;
      dtA_ = (float)dsp_row[qa];
      cA0 = C0[qa]; cA1 = C0[LL + qa];
      int qb = 64 + lane;
      dtB_ = (float)dsp_row[qb];
      cB0 = C0[qb]; cB1 = C0[LL + qb];
    }
    float cum = 0.f;
    for (int s = 0; s < CH - 1; s += 2){
      {
        float dt = dtA_;
        float4 c0 = cA0, c1 = cA1;
        if (s + 2 < CH){
          int q2 = (s + 2) * 64 + lane;
          dtA_ = (float)dsp_row[q2];
          cA0 = C0[q2]; cA1 = C0[LL + q2];
        }
        cum += dt;
        float Rc = __expf(-cum);
        float Cv[NS];
        unpack8(c0, Cv); unpack8(c1, Cv + 8);
        float p[NS];
        pow_tree(Rc, p);
        float s0 = 0.f, s1 = 0.f, s2 = 0.f, s3 = 0.f;
        #pragma unroll
        for (int n = 0; n < NS; ++n){
          float t = h[n] * p[n] * Cv[n];
          if      ((n & 3) == 0) s0 += t;
          else if ((n & 3) == 1) s1 += t;
          else if ((n & 3) == 2) s2 += t;
          else                   s3 += t;
        }
        int li = lane * CH + s;
        ysth[wv][li] = (h16)((float)ysth[wv][li] + (s0 + s1) + (s2 + s3));
      }
      {
        float dt = dtB_;
        float4 c0 = cB0, c1 = cB1;
        if (s + 3 < CH){
          int q3 = (s + 3) * 64 + lane;
          dtB_ = (float)dsp_row[q3];
          cB0 = C0[q3]; cB1 = C0[LL + q3];
        }
        cum += dt;
        float Rc = __expf(-cum);
        float Cv[NS];
        unpack8(c0, Cv); unpack8(c1, Cv + 8);
        float p[NS];
        pow_tree(Rc, p);
        float s0 = 0.f, s1 = 0.f, s2 = 0.f, s3 = 0.f;
        #pragma unroll
        for (int n = 0; n < NS; ++n){
          float t = h[n] * p[n] * Cv[n];
          if      ((n & 3) == 0) s0 += t;
          else if ((n & 3) == 1) s1 += t;
          else if ((n & 3) == 2) s2 += t;
          else                   s3 += t;
        }
        int li = lane * CH + s + 1;
        ysth[wv][li] = (h16)((float)ysth[wv][li] + (s0 + s1) + (s2 + s3));
      }
    }
    {
      const int s = CH - 1;
      cum += dtA_;
      float Rc = __expf(-cum);
      float Cv[NS];
      unpack8(cA0, Cv); unpack8(cA1, Cv + 8);
      float p[NS];
      pow_tree(Rc, p);
      float s0 = 0.f, s1 = 0.f, s2 = 0.f, s3 = 0.f;
      #pragma unroll
      for (int n = 0; n < NS; ++n){
        float t = h[n] * p[n] * Cv[n];
        if      ((n & 3) == 0) s0 += t;
        else if ((n & 3) == 1) s1 += t;
        else if ((n & 3) == 2) s2 += t;
        else                   s3 += t;
      }
      int li = lane * CH + s;
      ysth[wv][li] = (h16)((float)ysth[wv][li] + (s0 + s1) + (s2 + s3));
    }
  } else {
    float cum = 0.f;
    #pragma unroll 5
    for (int s = 0; s < CH; ++s){
      int q = s * 64 + lane;
      cum += (float)dsp_row[q];
      float Cv[NS];
      unpack8(C0[q], Cv); unpack8(C0[LL + q], Cv + 8);
      float s0 = 0.f, s1 = 0.f, s2 = 0.f, s3 = 0.f;
      #pragma unroll
      for (int n = 0; n < NS; ++n){
        float t = h[n] * __expf(cum * An[n]) * Cv[n];
        if      ((n & 3) == 0) s0 += t;
        else if ((n & 3) == 1) s1 += t;
        else if ((n & 3) == 2) s2 += t;
        else                   s3 += t;
      }
      int li = lane * CH + s;
      ysth[wv][li] = (h16)((float)ysth[wv][li] + (s0 + s1) + (s2 + s3));
    }
  }

  // flush OWN ystage in PIXEL order (no barrier — wave-private buffer).
  h16* yo = y_px + (size_t)chain * LL;
  for (int qq = lane; qq < LL; qq += 64){
    int l;
    if      (k == 0) l = qq;
    else if (k == 1) l = (qq % WW) * WW + qq / WW;
    else if (k == 2) l = LL - 1 - qq;
    else             { int qt = (qq % WW) * WW + qq / WW; l = LL - 1 - qt; }
    yo[qq] = ysth[wv][l];
  }
}

// ------ K4: FUSED merge + LayerNorm + cross SE + out_proj ---------------
// grid: (L/4, B) = 800 blocks, 256 thr.
__global__ void __launch_bounds__(256) k_mergeout(
    const h16* __restrict__ y_px, const float* __restrict__ sq,
    const float* __restrict__ fc1_w1, const float* __restrict__ fc1_w2,
    const float* __restrict__ fc2_w1, const float* __restrict__ fc2_w2,
    const float* __restrict__ n1g, const float* __restrict__ n1b,
    const float* __restrict__ n2g, const float* __restrict__ n2b,
    const float* __restrict__ wout, float* __restrict__ out){
  __shared__ float acc[2 * DIN][5];       // [(m*DIN+dd)][pp]
  __shared__ float yt[4][388];            // [pp][m*DIN+dd], GEMM operand
  __shared__ float ps[2][4][32], ps2[2][4][32];
  __shared__ float mu_s[2][4], inv_s[2][4];
  __shared__ float sqs[2][DIN];           // sq of the OTHER modality, per m
  __shared__ float hid[2][12];
  __shared__ float exc_s[2][DIN];
  int p0 = blockIdx.x * 4;
  int b  = blockIdx.y;
  int tid = threadIdx.x;
  for (int idx = tid; idx < 2 * DIN * 4; idx += 256){
    int pp = idx & 3, row = idx >> 2;
    int mm = (row >= DIN), dd = row - mm * DIN;
    const h16* yb = y_px + ((size_t)(mm * BN + b) * KK * DIN + dd) * LL + p0 + pp;
    acc[row][pp] = (float)yb[0] + (float)yb[(size_t)DIN * LL]
                 + (float)yb[2 * (size_t)DIN * LL] + (float)yb[3 * (size_t)DIN * LL];
  }
  for (int i = tid; i < 2 * DIN; i += 256){
    int mm = (i >= DIN), dd = i - mm * DIN;
    sqs[mm][dd] = sq[((1 - mm) * BN + b) * DIN + dd];
  }
  __syncthreads();
  if (tid < 24){
    int mm = tid / 12, j = tid - mm * 12;
    const float* w1 = (mm == 1 ? fc1_w1 : fc2_w1);
    float a = 0.f;
    for (int cch = 0; cch < DIN; ++cch) a += w1[j * DIN + cch] * sqs[mm][cch];
    hid[mm][j] = a * sigmoidf_(a);
  }
  {
    int pp = tid & 3, mm = (tid >> 2) & 1, g = tid >> 3;   // g in 0..31
    float s = 0.f, s2 = 0.f;
    #pragma unroll
    for (int j = 0; j < 6; ++j){
      float v = acc[mm * DIN + g * 6 + j][pp];
      s += v; s2 += v * v;
    }
    ps[mm][pp][g] = s; ps2[mm][pp][g] = s2;
  }
  __syncthreads();
  if (tid < 8){
    int mm = tid >> 2, pp = tid & 3;
    float s = 0.f, s2 = 0.f;
    #pragma unroll
    for (int g = 0; g < 32; ++g){ s += ps[mm][pp][g]; s2 += ps2[mm][pp][g]; }
    float mu  = s * (1.0f / DIN);
    float var = s2 * (1.0f / DIN) - mu * mu;
    mu_s[mm][pp] = mu; inv_s[mm][pp] = rsqrtf(var + 1e-5f);
  }
  for (int i = tid; i < 2 * DIN; i += 256){
    int mm = (i >= DIN), dd = i - mm * DIN;
    const float* w2 = (mm == 1 ? fc1_w2 : fc2_w2);
    float e = 0.f;
    #pragma unroll
    for (int j = 0; j < 12; ++j) e += w2[dd * 12 + j] * hid[mm][j];
    exc_s[mm][dd] = sigmoidf_(e);
  }
  __syncthreads();
  for (int idx = tid; idx < 2 * DIN * 4; idx += 256){
    int pp = idx & 3, row = idx >> 2;
    int mm = (row >= DIN), dd = row - mm * DIN;
    float g  = (mm ? n2g : n1g)[dd];
    float bb = (mm ? n2b : n1b)[dd];
    float v = (acc[row][pp] - mu_s[mm][pp]) * inv_s[mm][pp] * g + bb;
    yt[pp][row] = v * exc_s[mm][dd];
  }
  __syncthreads();
  int pp = tid & 3;
  int og = tid >> 2;
  const float4* yv = reinterpret_cast<const float4*>(yt[pp]);
  float a0 = 0.f, a1 = 0.f;
  if (og < 32){
    for (int cc = 0; cc < 96; ++cc){
      float4 x4 = yv[cc];
      float4 w40 = *reinterpret_cast<const float4*>(wout + og * 2 * DIN + cc * 4);
      float4 w41 = *reinterpret_cast<const float4*>(wout + (og + 64) * 2 * DIN + cc * 4);
      a0 += w40.x * x4.x + w40.y * x4.y + w40.z * x4.z + w40.w * x4.w;
      a1 += w41.x * x4.x + w41.y * x4.y + w41.z * x4.z + w41.w * x4.w;
    }
    out[((size_t)b * CIN + og) * LL + p0 + pp] = a0;
    out[((size_t)b * CIN + og + 64) * LL + p0 + pp] = a1;
  } else {
    for (int cc = 0; cc < 96; ++cc){
      float4 x4 = yv[cc];
      float4 w40 = *reinterpret_cast<const float4*>(wout + og * 2 * DIN + cc * 4);
      a0 += w40.x * x4.x + w40.y * x4.y + w40.z * x4.z + w40.w * x4.w;
    }
    out[((size_t)b * CIN + og) * LL + p0 + pp] = a0;
  }
}

extern "C" void kernel_launch(void* const* d_in, const int* in_sizes, int n_in,
                              void* d_out, int out_size, void* d_ws, size_t ws_size,
                              hipStream_t stream){
  const float* x_rgb   = (const float*)d_in[0];
  const float* x_e     = (const float*)d_in[1];
  const float* in_w    = (const float*)d_in[2];
  const float* in_mx_w = (const float*)d_in[3];
  const float* conv_w  = (const float*)d_in[4];
  const float* conv_b  = (const float*)d_in[5];
  const float* xp1     = (const float*)d_in[6];
  const float* xp2     = (const float*)d_in[7];
  const float* dtw1    = (const float*)d_in[8];
  const float* dtb1    = (const float*)d_in[9];
  const float* dtw2    = (const float*)d_in[10];
  const float* dtb2    = (const float*)d_in[11];
  const float* Alog1   = (const float*)d_in[12];
  const float* Alog2   = (const float*)d_in[13];
  const float* D1      = (const float*)d_in[14];
  const float* D2      = (const float*)d_in[15];
  const float* n1g     = (const float*)d_in[16];
  const float* n1b     = (const float*)d_in[17];
  const float* n2g     = (const float*)d_in[18];
  const float* n2b     = (const float*)d_in[19];
  const float* fc1_w1  = (const float*)d_in[20];
  const float* fc1_w2  = (const float*)d_in[21];
  const float* fc2_w1  = (const float*)d_in[22];
  const float* fc2_w2  = (const float*)d_in[23];
  const float* wout    = (const float*)d_in[24];

  float* ws = (float*)d_ws;
  h16*   u_chA   = (h16*)(ws);
  h16*   u_chT   = (h16*)(ws + 614400);
  h16*   y_px    = (h16*)(ws + 3686400);
  h16*   B_ch    = (h16*)(ws + 8601600);
  h16*   C_ch    = (h16*)(ws + 8806400);
  h16*   dsp     = (h16*)(ws + 9011200);
  float* sq      = ws + 11468800;

  k_conv    <<<dim3(DIN, 2 * BN), 256, 0, stream>>>(x_rgb, x_e, in_w, in_mx_w,
                                                    conv_w, conv_b,
                                                    u_chA, u_chT, sq);
  k_xproj   <<<dim3(25, KK * 2, 2 * BN), 256, 0, stream>>>(u_chA, u_chT, xp1, xp2,
                                                           dtw1, dtb1, dtw2, dtb2,
                                                           B_ch, C_ch, dsp);
  k_scan    <<<768, 256, 0, stream>>>(u_chA, u_chT, dsp, B_ch, C_ch,
                                      Alog1, Alog2, D1, D2, y_px);
  k_mergeout<<<dim3(LL / 4, BN), 256, 0, stream>>>(y_px, sq,
                                                   fc1_w1, fc1_w2, fc2_w1, fc2_w2,
                                                   n1g, n1b, n2g, n2b,
                                                   wout, (float*)d_out);
}

// Round 27
// 140.050 us; speedup vs baseline: 1.2268x; 1.2268x over previous
//
#include <hip/hip_runtime.h>
#include <math.h>

#define BN   2
#define CIN  96
#define HH   40
#define WW   40
#define LL   1600
#define DIN  192
#define NS   16
#define RR   6
#define KK   4
#define CH   25   // chunk length per lane (LL/64)

typedef _Float16 h16;

__device__ __forceinline__ float sigmoidf_(float x){ return 1.0f/(1.0f+expf(-x)); }
__device__ __forceinline__ float softplus_fast(float x){
  return x > 20.0f ? x : __logf(1.0f + __expf(x));
}

// p[i] = R^(i+1) for i=0..15, log-depth tree (depth ~4, 15 muls)
__device__ __forceinline__ void pow_tree(float R, float* p){
  float R2 = R * R;
  float R4 = R2 * R2;
  float R8 = R4 * R4;
  p[0]  = R;        p[1]  = R2;       p[2]  = R2 * R;   p[3]  = R4;
  p[4]  = R4 * R;   p[5]  = R4 * R2;  p[6]  = R4 * p[2];p[7]  = R8;
  p[8]  = R8 * R;   p[9]  = R8 * R2;  p[10] = R8 * p[2];p[11] = R8 * R4;
  p[12] = R8 * p[4];p[13] = R8 * p[5];p[14] = R8 * p[6];p[15] = R8 * R8;
}

__device__ __forceinline__ void unpack8(float4 v, float* dst){
  const h16* hp = reinterpret_cast<const h16*>(&v);
  #pragma unroll
  for (int i = 0; i < 8; ++i) dst[i] = (float)hp[i];
}

// ---------------- K1: in_proj (1x1) for both modalities ----------------
// grid: (L/8, 2*B) = 800 blocks, 256 thr. xproj layout [mb][o][p] (HALF)
__global__ void k_inproj(const float* __restrict__ x_rgb, const float* __restrict__ x_e,
                         const float* __restrict__ w_rgb, const float* __restrict__ w_e,
                         h16* __restrict__ xproj){
  __shared__ float xin[8][100];           // [px][c], padded row
  int l0 = blockIdx.x * 8;
  int mb = blockIdx.y;                    // m*BN + b
  int m = mb / BN, b = mb % BN;
  const float* xsrc = (m == 0 ? x_rgb : x_e) + (size_t)b * CIN * LL;
  const float* w    = (m == 0 ? w_rgb : w_e);
  for (int idx = threadIdx.x; idx < CIN * 8; idx += 256){
    int c = idx >> 3, px = idx & 7;
    xin[px][c] = xsrc[c * LL + l0 + px];
  }
  __syncthreads();
  int px = threadIdx.x & 7;
  int o0 = (threadIdx.x >> 3) * 6;        // 32 groups x 6 outputs
  float acc[6];
  #pragma unroll
  for (int i = 0; i < 6; ++i) acc[i] = 0.f;
  const float4* xv = reinterpret_cast<const float4*>(xin[px]);
  for (int cc = 0; cc < CIN / 4; ++cc){
    float4 x4 = xv[cc];
    #pragma unroll
    for (int i = 0; i < 6; ++i){
      float4 w4 = *reinterpret_cast<const float4*>(w + (o0 + i) * CIN + cc * 4);
      acc[i] += w4.x * x4.x + w4.y * x4.y + w4.z * x4.z + w4.w * x4.w;
    }
  }
  #pragma unroll
  for (int i = 0; i < 6; ++i)
    xproj[((size_t)mb * DIN + o0 + i) * LL + l0 + px] = (h16)acc[i];
}

// ------ K2: depthwise 3x3 + bias + SiLU; emit HALF u_chA/u_chT + SE mean
// grid: (DIN, 2*B), block 256
__global__ void k_conv(const h16* __restrict__ xproj, const float* __restrict__ conv_w,
                       const float* __restrict__ conv_b, h16* __restrict__ u_chA,
                       h16* __restrict__ u_chT, float* __restrict__ sq){
  __shared__ float pl[LL];
  __shared__ float sact[LL + HH];    // padded: index l + l/40
  __shared__ float red[4];
  int d  = blockIdx.x;
  int mb = blockIdx.y;
  const h16* src = xproj + ((size_t)mb * DIN + d) * LL;
  for (int p = threadIdx.x; p < LL; p += blockDim.x) pl[p] = (float)src[p];
  __syncthreads();
  float cw[9];
  #pragma unroll
  for (int j = 0; j < 9; ++j) cw[j] = conv_w[d * 9 + j];
  float bias = conv_b[d];
  float lsum = 0.f;
  for (int p = threadIdx.x; p < LL; p += blockDim.x){
    int py = p / WW, px = p % WW;
    float acc = bias;
    #pragma unroll
    for (int dy = -1; dy <= 1; ++dy){
      int yy = py + dy;
      if (yy < 0 || yy >= HH) continue;
      #pragma unroll
      for (int dx = -1; dx <= 1; ++dx){
        int xx = px + dx;
        if (xx < 0 || xx >= WW) continue;
        acc += cw[(dy + 1) * 3 + (dx + 1)] * pl[yy * WW + xx];
      }
    }
    float s = acc * sigmoidf_(acc);
    sact[p + p / WW] = s;
    lsum += s;
  }
  #pragma unroll
  for (int off = 32; off; off >>= 1) lsum += __shfl_down(lsum, off);
  if ((threadIdx.x & 63) == 0) red[threadIdx.x >> 6] = lsum;
  __syncthreads();
  if (threadIdx.x == 0)
    sq[mb * DIN + d] = (red[0] + red[1] + red[2] + red[3]) * (1.0f / LL);
  size_t po = ((size_t)mb * DIN + d) * LL;
  h16* uA = u_chA + po;
  h16* uT = u_chT + po;
  for (int q = threadIdx.x; q < LL; q += blockDim.x){
    int l = (q & 63) * CH + (q >> 6);
    uA[q] = (h16)sact[l + l / WW];
    int pt = (l % WW) * WW + l / WW;
    uT[q] = (h16)sact[pt + pt / WW];
  }
}

// ------ K3: x_proj + FUSED dt-projection/softplus — Q-TILED --------------
// grid: (25, K*2, 2*B), block 256. Block bx covers chunk indices
// q in [64*bx, 64*bx+64): x reads straight from u_chA/u_chT (coalesced,
// reversed dirs via chunk-map identity); B/C/dsp writes q-contiguous.
__global__ void k_xproj(const h16* __restrict__ u_chA, const h16* __restrict__ u_chT,
                        const float* __restrict__ xp1, const float* __restrict__ xp2,
                        const float* __restrict__ dtw1, const float* __restrict__ dtb1,
                        const float* __restrict__ dtw2, const float* __restrict__ dtb2,
                        h16* __restrict__ B_ch, h16* __restrict__ C_ch,
                        h16* __restrict__ dsp_all){
  __shared__ h16 xs[DIN][64];           // 24 KB staged tile
  __shared__ float td[RR][64];
  int bx = blockIdx.x;                  // s-row; q0 = bx*64
  int k  = blockIdx.y >> 1;
  int hf = blockIdx.y & 1;              // channel half
  int mb = blockIdx.z; int m = mb / BN;
  const float* xw = (m == 0 ? xp1 : xp2) + k * 38 * DIN;
  const h16* xa = ((k & 1) ? u_chT : u_chA) + (size_t)mb * DIN * LL;
  bool rev = (k >= 2);
  int qrbase = rev ? ((24 - bx) * 64) : (bx * 64);
  for (int idx = threadIdx.x; idx < DIN * 64; idx += 256){
    int dd = idx >> 6, sl = idx & 63;
    int qr = rev ? (qrbase + 63 - sl) : (qrbase + sl);
    xs[dd][sl] = xa[(size_t)dd * LL + qr];
  }
  __syncthreads();
  int ll = threadIdx.x & 63;
  int g  = __builtin_amdgcn_readfirstlane(threadIdx.x >> 6);  // wave-uniform
  int c0 = (hf * 4 + g) * 5;            // 8 slots x 5 channels (40 >= 38)
  float acc[5];
  #pragma unroll
  for (int i = 0; i < 5; ++i) acc[i] = 0.f;
  for (int dd = 0; dd < DIN; ++dd){
    float xv = (float)xs[dd][ll];
    #pragma unroll
    for (int i = 0; i < 5; ++i){
      int cc = c0 + i; if (cc > 37) cc = 37;      // clamp (uniform, in-bounds)
      acc[i] += xw[cc * DIN + dd] * xv;           // scalar s_load
    }
  }
  int mbk = mb * KK + k;
  int q = bx * 64 + ll;                 // chunk index (contiguous per wave)
  int nc = 38 - c0; if (nc > 5) nc = 5;
  for (int i = 0; i < nc; ++i){
    int c = c0 + i;
    float v = acc[i];
    if (c < RR){
      td[c][ll] = v;                    // dt rows stay in LDS (half 0 only)
    } else if (c < RR + NS){
      int n = c - RR;
      B_ch[(((size_t)mbk * 2 + (n >> 3)) * LL + q) * 8 + (n & 7)] = (h16)v;
    } else {
      int n = c - RR - NS;
      C_ch[(((size_t)mbk * 2 + (n >> 3)) * LL + q) * 8 + (n & 7)] = (h16)v;
    }
  }
  if (hf == 0){
    __syncthreads();
    const float* dtw = (m == 0 ? dtw1 : dtw2);
    const float* dtb = (m == 0 ? dtb1 : dtb2);
    h16* dsp = dsp_all + (size_t)mbk * DIN * LL;
    for (int idx = threadIdx.x; idx < DIN * 64; idx += 256){
      int dd = __builtin_amdgcn_readfirstlane(idx >> 6);   // wave-uniform
      int px = idx & 63;
      int kd = k * DIN + dd;
      const float* w = dtw + kd * RR;
      float a = dtb[kd];
      #pragma unroll
      for (int r = 0; r < RR; ++r) a += w[r] * td[r][px];
      dsp[(size_t)dd * LL + bx * 64 + px] = (h16)softplus_fast(a);  // q-order
    }
  }
}

// ---------------- K4: chunked parallel selective scan -------------------
// ONE WAVE PER CHAIN, 16 states in registers, wave-private LDS (no barrier,
// no atomic). q-ordered dsp joins the DEPTH-2 pipeline directly.
// grid: 768 blocks of 256. y_px HALF [chain][pixel]
__global__ void __launch_bounds__(256, 3) k_scan(
    const h16* __restrict__ u_chA, const h16* __restrict__ u_chT,
    const h16* __restrict__ dsp_all, const h16* __restrict__ B_ch,
    const h16* __restrict__ C_ch,
    const float* __restrict__ Alog1, const float* __restrict__ Alog2,
    const float* __restrict__ D1, const float* __restrict__ D2,
    h16* __restrict__ y_px){
  __shared__ h16 ysth[4][LL];               // [wave][l]  (wave-private)
  int wv   = threadIdx.x >> 6;
  int lane = threadIdx.x & 63;
  int chain = blockIdx.x * 4 + wv;          // = (mb*KK + k)*DIN + d
  int d   = chain % DIN;
  int mbk = chain / DIN;
  int k   = mbk % KK;
  int mb  = mbk / KK;
  int m = mb / BN, b = mb % BN;
  int kd = k * DIN + d;
  bool rev = (k >= 2);

  const float* Alog = (m == 0 ? Alog1 : Alog2) + kd * NS;
  float An[NS];
  bool fastA = true;
  #pragma unroll
  for (int n = 0; n < NS; ++n){
    An[n] = -__expf(Alog[n]);
    fastA = fastA && (fabsf(An[n] + (float)(n + 1)) <= 1e-4f * (float)(n + 1));
  }
  float Dv = (m == 0 ? D2 : D1)[kd];

  const h16* dsp_row = dsp_all + (size_t)chain * LL;   // q-ordered
  const float4* B0 = reinterpret_cast<const float4*>(B_ch) + (size_t)mbk * 2 * LL;
  int mbk_o = ((1 - m) * BN + b) * KK + k;              // other modality's C
  const float4* C0 = reinterpret_cast<const float4*>(C_ch) + (size_t)mbk_o * 2 * LL;
  const h16* urow = ((k & 1) ? u_chT : u_chA) + ((size_t)mb * DIN + d) * LL;

  float h[NS];
  #pragma unroll
  for (int n = 0; n < NS; ++n) h[n] = 0.f;
  float Sdt = 0.f;

  if (fastA){
    // ---- phase 1, depth-2 pipeline (named A/B sets, static indices) ----
    float4 bA0, bA1, cA0, cA1, bB0, bB1, cB0, cB1;
    float uA_, uB_, dtA_, dtB_;
    {
      int qa = lane;
      dtA_ = (float)dsp_row[qa];
      uA_  = (float)urow[rev ? (LL - 1 - qa) : qa];
      bA0 = B0[qa]; bA1 = B0[LL + qa];
      cA0 = C0[qa]; cA1 = C0[LL + qa];
      int qb = 64 + lane;
      dtB_ = (float)dsp_row[qb];
      uB_  = (float)urow[rev ? (LL - 1 - qb) : qb];
      bB0 = B0[qb]; bB1 = B0[LL + qb];
      cB0 = C0[qb]; cB1 = C0[LL + qb];
    }
    for (int s = 0; s < CH - 1; s += 2){
      {
        float dt = dtA_, u = uA_;
        float4 b0 = bA0, b1 = bA1, c0 = cA0, c1 = cA1;
        if (s + 2 < CH){
          int q2 = (s + 2) * 64 + lane;
          dtA_ = (float)dsp_row[q2];
          uA_  = (float)urow[rev ? (LL - 1 - q2) : q2];
          bA0 = B0[q2]; bA1 = B0[LL + q2];
          cA0 = C0[q2]; cA1 = C0[LL + q2];
        }
        Sdt += dt;
        float du = dt * u;
        float Bv[NS], Cv[NS];
        unpack8(b0, Bv); unpack8(b1, Bv + 8);
        unpack8(c0, Cv); unpack8(c1, Cv + 8);
        float p[NS];
        pow_tree(__expf(-dt), p);
        float y0 = Dv * u, y1 = 0.f, y2 = 0.f, y3 = 0.f;
        #pragma unroll
        for (int n = 0; n < NS; ++n){
          h[n] = p[n] * h[n] + du * Bv[n];
          float t = h[n] * Cv[n];
          if      ((n & 3) == 0) y0 += t;
          else if ((n & 3) == 1) y1 += t;
          else if ((n & 3) == 2) y2 += t;
          else                   y3 += t;
        }
        ysth[wv][lane * CH + s] = (h16)((y0 + y1) + (y2 + y3));
      }
      {
        float dt = dtB_, u = uB_;
        float4 b0 = bB0, b1 = bB1, c0 = cB0, c1 = cB1;
        if (s + 3 < CH){
          int q3 = (s + 3) * 64 + lane;
          dtB_ = (float)dsp_row[q3];
          uB_  = (float)urow[rev ? (LL - 1 - q3) : q3];
          bB0 = B0[q3]; bB1 = B0[LL + q3];
          cB0 = C0[q3]; cB1 = C0[LL + q3];
        }
        Sdt += dt;
        float du = dt * u;
        float Bv[NS], Cv[NS];
        unpack8(b0, Bv); unpack8(b1, Bv + 8);
        unpack8(c0, Cv); unpack8(c1, Cv + 8);
        float p[NS];
        pow_tree(__expf(-dt), p);
        float y0 = Dv * u, y1 = 0.f, y2 = 0.f, y3 = 0.f;
        #pragma unroll
        for (int n = 0; n < NS; ++n){
          h[n] = p[n] * h[n] + du * Bv[n];
          float t = h[n] * Cv[n];
          if      ((n & 3) == 0) y0 += t;
          else if ((n & 3) == 1) y1 += t;
          else if ((n & 3) == 2) y2 += t;
          else                   y3 += t;
        }
        ysth[wv][lane * CH + s + 1] = (h16)((y0 + y1) + (y2 + y3));
      }
    }
    {
      const int s = CH - 1;
      float dt = dtA_, u = uA_;
      Sdt += dt;
      float du = dt * u;
      float Bv[NS], Cv[NS];
      unpack8(bA0, Bv); unpack8(bA1, Bv + 8);
      unpack8(cA0, Cv); unpack8(cA1, Cv + 8);
      float p[NS];
      pow_tree(__expf(-dt), p);
      float y0 = Dv * u, y1 = 0.f, y2 = 0.f, y3 = 0.f;
      #pragma unroll
      for (int n = 0; n < NS; ++n){
        h[n] = p[n] * h[n] + du * Bv[n];
        float t = h[n] * Cv[n];
        if      ((n & 3) == 0) y0 += t;
        else if ((n & 3) == 1) y1 += t;
        else if ((n & 3) == 2) y2 += t;
        else                   y3 += t;
      }
      ysth[wv][lane * CH + s] = (h16)((y0 + y1) + (y2 + y3));
    }
  } else {
    #pragma unroll 5
    for (int s = 0; s < CH; ++s){
      int q = s * 64 + lane;
      float dt = (float)dsp_row[q];
      Sdt += dt;
      float u  = (float)urow[rev ? (LL - 1 - q) : q];
      float du = dt * u;
      float Bv[NS], Cv[NS];
      unpack8(B0[q], Bv); unpack8(B0[LL + q], Bv + 8);
      unpack8(C0[q], Cv); unpack8(C0[LL + q], Cv + 8);
      float y0 = Dv * u, y1 = 0.f, y2 = 0.f, y3 = 0.f;
      #pragma unroll
      for (int n = 0; n < NS; ++n){
        float dA = __expf(dt * An[n]);
        h[n] = dA * h[n] + du * Bv[n];
        float t = h[n] * Cv[n];
        if      ((n & 3) == 0) y0 += t;
        else if ((n & 3) == 1) y1 += t;
        else if ((n & 3) == 2) y2 += t;
        else                   y3 += t;
      }
      ysth[wv][lane * CH + s] = (h16)((y0 + y1) + (y2 + y3));
    }
  }
  float aP[NS];
  if (fastA){
    pow_tree(__expf(-Sdt), aP);
  } else {
    #pragma unroll
    for (int n = 0; n < NS; ++n) aP[n] = __expf(Sdt * An[n]);
  }

  // Kogge-Stone inclusive scan of (aP,h) across 64 lanes (chunk order)
  #pragma unroll
  for (int off = 1; off < 64; off <<= 1){
    #pragma unroll
    for (int n = 0; n < NS; ++n){
      float ap = __shfl_up(aP[n], off);
      float bp = __shfl_up(h[n],  off);
      if (lane >= off){
        h[n]  = aP[n] * bp + h[n];
        aP[n] = aP[n] * ap;
      }
    }
  }
  // carry-in for this chunk = inclusive result of previous lane
  #pragma unroll
  for (int n = 0; n < NS; ++n){
    float v = __shfl_up(h[n], 1);
    h[n] = (lane == 0) ? 0.f : v;      // h[] now holds the carry
  }

  // phase 2: correction pass — ysth[l] += sum_n carry[n]*E_s^(n+1)*C[n]
  if (fastA){
    float4 cA0, cA1, cB0, cB1;
    float dtA_, dtB_;
    {
      int qa = lane;
      dtA_ = (float)dsp_row[qa];
      cA0 = C0[qa]; cA1 = C0[LL + qa];
      int qb = 64 + lane;
      dtB_ = (float)dsp_row[qb];
      cB0 = C0[qb]; cB1 = C0[LL + qb];
    }
    float cum = 0.f;
    for (int s = 0; s < CH - 1; s += 2){
      {
        float dt = dtA_;
        float4 c0 = cA0, c1 = cA1;
        if (s + 2 < CH){
          int q2 = (s + 2) * 64 + lane;
          dtA_ = (float)dsp_row[q2];
          cA0 = C0[q2]; cA1 = C0[LL + q2];
        }
        cum += dt;
        float Rc = __expf(-cum);
        float Cv[NS];
        unpack8(c0, Cv); unpack8(c1, Cv + 8);
        float p[NS];
        pow_tree(Rc, p);
        float s0 = 0.f, s1 = 0.f, s2 = 0.f, s3 = 0.f;
        #pragma unroll
        for (int n = 0; n < NS; ++n){
          float t = h[n] * p[n] * Cv[n];
          if      ((n & 3) == 0) s0 += t;
          else if ((n & 3) == 1) s1 += t;
          else if ((n & 3) == 2) s2 += t;
          else                   s3 += t;
        }
        int li = lane * CH + s;
        ysth[wv][li] = (h16)((float)ysth[wv][li] + (s0 + s1) + (s2 + s3));
      }
      {
        float dt = dtB_;
        float4 c0 = cB0, c1 = cB1;
        if (s + 3 < CH){
          int q3 = (s + 3) * 64 + lane;
          dtB_ = (float)dsp_row[q3];
          cB0 = C0[q3]; cB1 = C0[LL + q3];
        }
        cum += dt;
        float Rc = __expf(-cum);
        float Cv[NS];
        unpack8(c0, Cv); unpack8(c1, Cv + 8);
        float p[NS];
        pow_tree(Rc, p);
        float s0 = 0.f, s1 = 0.f, s2 = 0.f, s3 = 0.f;
        #pragma unroll
        for (int n = 0; n < NS; ++n){
          float t = h[n] * p[n] * Cv[n];
          if      ((n & 3) == 0) s0 += t;
          else if ((n & 3) == 1) s1 += t;
          else if ((n & 3) == 2) s2 += t;
          else                   s3 += t;
        }
        int li = lane * CH + s + 1;
        ysth[wv][li] = (h16)((float)ysth[wv][li] + (s0 + s1) + (s2 + s3));
      }
    }
    {
      const int s = CH - 1;
      cum += dtA_;
      float Rc = __expf(-cum);
      float Cv[NS];
      unpack8(cA0, Cv); unpack8(cA1, Cv + 8);
      float p[NS];
      pow_tree(Rc, p);
      float s0 = 0.f, s1 = 0.f, s2 = 0.f, s3 = 0.f;
      #pragma unroll
      for (int n = 0; n < NS; ++n){
        float t = h[n] * p[n] * Cv[n];
        if      ((n & 3) == 0) s0 += t;
        else if ((n & 3) == 1) s1 += t;
        else if ((n & 3) == 2) s2 += t;
        else                   s3 += t;
      }
      int li = lane * CH + s;
      ysth[wv][li] = (h16)((float)ysth[wv][li] + (s0 + s1) + (s2 + s3));
    }
  } else {
    float cum = 0.f;
    #pragma unroll 5
    for (int s = 0; s < CH; ++s){
      int q = s * 64 + lane;
      cum += (float)dsp_row[q];
      float Cv[NS];
      unpack8(C0[q], Cv); unpack8(C0[LL + q], Cv + 8);
      float s0 = 0.f, s1 = 0.f, s2 = 0.f, s3 = 0.f;
      #pragma unroll
      for (int n = 0; n < NS; ++n){
        float t = h[n] * __expf(cum * An[n]) * Cv[n];
        if      ((n & 3) == 0) s0 += t;
        else if ((n & 3) == 1) s1 += t;
        else if ((n & 3) == 2) s2 += t;
        else                   s3 += t;
      }
      int li = lane * CH + s;
      ysth[wv][li] = (h16)((float)ysth[wv][li] + (s0 + s1) + (s2 + s3));
    }
  }

  // flush OWN ystage in PIXEL order (no barrier — wave-private buffer).
  h16* yo = y_px + (size_t)chain * LL;
  for (int qq = lane; qq < LL; qq += 64){
    int l;
    if      (k == 0) l = qq;
    else if (k == 1) l = (qq % WW) * WW + qq / WW;
    else if (k == 2) l = LL - 1 - qq;
    else             { int qt = (qq % WW) * WW + qq / WW; l = LL - 1 - qt; }
    yo[qq] = ysth[wv][l];
  }
}

// ------ K5: FUSED merge + LayerNorm + cross SE + out_proj ---------------
// grid: (L/4, B) = 800 blocks, 256 thr.
__global__ void __launch_bounds__(256) k_mergeout(
    const h16* __restrict__ y_px, const float* __restrict__ sq,
    const float* __restrict__ fc1_w1, const float* __restrict__ fc1_w2,
    const float* __restrict__ fc2_w1, const float* __restrict__ fc2_w2,
    const float* __restrict__ n1g, const float* __restrict__ n1b,
    const float* __restrict__ n2g, const float* __restrict__ n2b,
    const float* __restrict__ wout, float* __restrict__ out){
  __shared__ float acc[2 * DIN][5];       // [(m*DIN+dd)][pp]
  __shared__ float yt[4][388];            // [pp][m*DIN+dd], GEMM operand
  __shared__ float ps[2][4][32], ps2[2][4][32];
  __shared__ float mu_s[2][4], inv_s[2][4];
  __shared__ float sqs[2][DIN];           // sq of the OTHER modality, per m
  __shared__ float hid[2][12];
  __shared__ float exc_s[2][DIN];
  int p0 = blockIdx.x * 4;
  int b  = blockIdx.y;
  int tid = threadIdx.x;
  for (int idx = tid; idx < 2 * DIN * 4; idx += 256){
    int pp = idx & 3, row = idx >> 2;
    int mm = (row >= DIN), dd = row - mm * DIN;
    const h16* yb = y_px + ((size_t)(mm * BN + b) * KK * DIN + dd) * LL + p0 + pp;
    acc[row][pp] = (float)yb[0] + (float)yb[(size_t)DIN * LL]
                 + (float)yb[2 * (size_t)DIN * LL] + (float)yb[3 * (size_t)DIN * LL];
  }
  for (int i = tid; i < 2 * DIN; i += 256){
    int mm = (i >= DIN), dd = i - mm * DIN;
    sqs[mm][dd] = sq[((1 - mm) * BN + b) * DIN + dd];
  }
  __syncthreads();
  if (tid < 24){
    int mm = tid / 12, j = tid - mm * 12;
    const float* w1 = (mm == 1 ? fc1_w1 : fc2_w1);
    float a = 0.f;
    for (int cch = 0; cch < DIN; ++cch) a += w1[j * DIN + cch] * sqs[mm][cch];
    hid[mm][j] = a * sigmoidf_(a);
  }
  {
    int pp = tid & 3, mm = (tid >> 2) & 1, g = tid >> 3;   // g in 0..31
    float s = 0.f, s2 = 0.f;
    #pragma unroll
    for (int j = 0; j < 6; ++j){
      float v = acc[mm * DIN + g * 6 + j][pp];
      s += v; s2 += v * v;
    }
    ps[mm][pp][g] = s; ps2[mm][pp][g] = s2;
  }
  __syncthreads();
  if (tid < 8){
    int mm = tid >> 2, pp = tid & 3;
    float s = 0.f, s2 = 0.f;
    #pragma unroll
    for (int g = 0; g < 32; ++g){ s += ps[mm][pp][g]; s2 += ps2[mm][pp][g]; }
    float mu  = s * (1.0f / DIN);
    float var = s2 * (1.0f / DIN) - mu * mu;
    mu_s[mm][pp] = mu; inv_s[mm][pp] = rsqrtf(var + 1e-5f);
  }
  for (int i = tid; i < 2 * DIN; i += 256){
    int mm = (i >= DIN), dd = i - mm * DIN;
    const float* w2 = (mm == 1 ? fc1_w2 : fc2_w2);
    float e = 0.f;
    #pragma unroll
    for (int j = 0; j < 12; ++j) e += w2[dd * 12 + j] * hid[mm][j];
    exc_s[mm][dd] = sigmoidf_(e);
  }
  __syncthreads();
  for (int idx = tid; idx < 2 * DIN * 4; idx += 256){
    int pp = idx & 3, row = idx >> 2;
    int mm = (row >= DIN), dd = row - mm * DIN;
    float g  = (mm ? n2g : n1g)[dd];
    float bb = (mm ? n2b : n1b)[dd];
    float v = (acc[row][pp] - mu_s[mm][pp]) * inv_s[mm][pp] * g + bb;
    yt[pp][row] = v * exc_s[mm][dd];
  }
  __syncthreads();
  int pp = tid & 3;
  int og = tid >> 2;
  const float4* yv = reinterpret_cast<const float4*>(yt[pp]);
  float a0 = 0.f, a1 = 0.f;
  if (og < 32){
    for (int cc = 0; cc < 96; ++cc){
      float4 x4 = yv[cc];
      float4 w40 = *reinterpret_cast<const float4*>(wout + og * 2 * DIN + cc * 4);
      float4 w41 = *reinterpret_cast<const float4*>(wout + (og + 64) * 2 * DIN + cc * 4);
      a0 += w40.x * x4.x + w40.y * x4.y + w40.z * x4.z + w40.w * x4.w;
      a1 += w41.x * x4.x + w41.y * x4.y + w41.z * x4.z + w41.w * x4.w;
    }
    out[((size_t)b * CIN + og) * LL + p0 + pp] = a0;
    out[((size_t)b * CIN + og + 64) * LL + p0 + pp] = a1;
  } else {
    for (int cc = 0; cc < 96; ++cc){
      float4 x4 = yv[cc];
      float4 w40 = *reinterpret_cast<const float4*>(wout + og * 2 * DIN + cc * 4);
      a0 += w40.x * x4.x + w40.y * x4.y + w40.z * x4.z + w40.w * x4.w;
    }
    out[((size_t)b * CIN + og) * LL + p0 + pp] = a0;
  }
}

extern "C" void kernel_launch(void* const* d_in, const int* in_sizes, int n_in,
                              void* d_out, int out_size, void* d_ws, size_t ws_size,
                              hipStream_t stream){
  const float* x_rgb   = (const float*)d_in[0];
  const float* x_e     = (const float*)d_in[1];
  const float* in_w    = (const float*)d_in[2];
  const float* in_mx_w = (const float*)d_in[3];
  const float* conv_w  = (const float*)d_in[4];
  const float* conv_b  = (const float*)d_in[5];
  const float* xp1     = (const float*)d_in[6];
  const float* xp2     = (const float*)d_in[7];
  const float* dtw1    = (const float*)d_in[8];
  const float* dtb1    = (const float*)d_in[9];
  const float* dtw2    = (const float*)d_in[10];
  const float* dtb2    = (const float*)d_in[11];
  const float* Alog1   = (const float*)d_in[12];
  const float* Alog2   = (const float*)d_in[13];
  const float* D1      = (const float*)d_in[14];
  const float* D2      = (const float*)d_in[15];
  const float* n1g     = (const float*)d_in[16];
  const float* n1b     = (const float*)d_in[17];
  const float* n2g     = (const float*)d_in[18];
  const float* n2b     = (const float*)d_in[19];
  const float* fc1_w1  = (const float*)d_in[20];
  const float* fc1_w2  = (const float*)d_in[21];
  const float* fc2_w1  = (const float*)d_in[22];
  const float* fc2_w2  = (const float*)d_in[23];
  const float* wout    = (const float*)d_in[24];

  float* ws = (float*)d_ws;
  h16*   u_chA   = (h16*)(ws);
  h16*   u_chT   = (h16*)(ws + 614400);
  h16*   xproj   = (h16*)(ws + 2457600);
  h16*   y_px    = (h16*)(ws + 3686400);
  h16*   B_ch    = (h16*)(ws + 8601600);
  h16*   C_ch    = (h16*)(ws + 8806400);
  h16*   dsp     = (h16*)(ws + 9011200);
  float* sq      = ws + 11468800;

  k_inproj  <<<dim3(LL / 8, 2 * BN), 256, 0, stream>>>(x_rgb, x_e, in_w, in_mx_w, xproj);
  k_conv    <<<dim3(DIN, 2 * BN), 256, 0, stream>>>(xproj, conv_w, conv_b,
                                                    u_chA, u_chT, sq);
  k_xproj   <<<dim3(25, KK * 2, 2 * BN), 256, 0, stream>>>(u_chA, u_chT, xp1, xp2,
                                                           dtw1, dtb1, dtw2, dtb2,
                                                           B_ch, C_ch, dsp);
  k_scan    <<<768, 256, 0, stream>>>(u_chA, u_chT, dsp, B_ch, C_ch,
                                      Alog1, Alog2, D1, D2, y_px);
  k_mergeout<<<dim3(LL / 4, BN), 256, 0, stream>>>(y_px, sq,
                                                   fc1_w1, fc1_w2, fc2_w1, fc2_w2,
                                                   n1g, n1b, n2g, n2b,
                                                   wout, (float*)d_out);
}